// Round 6
// baseline (267.034 us; speedup 1.0000x reference)
//
#include <hip/hip_runtime.h>
#include <cstdint>
#include <cmath>

// Problem constants
constexpr int TT   = 256;   // tokens
constexpr int HD   = 1024;  // hidden
constexpr int IDIM = 512;   // intermediate
constexpr int NE   = 32;    // experts
constexpr int NGRP = 8;
constexpr int TKG  = 4;
constexpr int TOPK = 8;
constexpr float RSCALE = 2.5f;

constexpr int NSX  = HD / 32;     // 32 k-slabs in Xe
constexpr int NSA  = IDIM / 32;   // 16 k-slabs in A
constexpr int SLAB = 16 * 64 * 8; // halves per (expert, slab): 16 mt-tiles x 64 lanes x 8

typedef float    f32x4 __attribute__((ext_vector_type(4)));
typedef _Float16 half8 __attribute__((ext_vector_type(8)));

// Workspace layout (bytes)
constexpr size_t WS_CNT   = 0;                                 // NE ints (zeroed)
constexpr size_t WS_TOK   = 256;                               // NE*TT ints
constexpr size_t WS_WL    = WS_TOK   + (size_t)NE * TT * 4;    // NE*TT floats
constexpr size_t WS_TSLOT = WS_WL    + (size_t)NE * TT * 4;    // TT*TOPK ints
constexpr size_t WS_OFFS  = WS_TSLOT + (size_t)TT * TOPK * 4;  // NE ints (pad 256)
constexpr size_t WS_XE    = WS_OFFS  + 256;                    // 16 MB Xe; Y aliases this after gateup
constexpr size_t WS_A     = WS_XE + (size_t)NE * NSX * SLAB * 2; // 8 MB A
// Y = f32[2048][HD] at WS_XE (8 MB <= 16 MB Xe region, Xe dead after k_gateup)

// global->LDS direct staging, 16B per lane (dest = wave-uniform base + lane*16)
#define GLOAD16(GP, LP) __builtin_amdgcn_global_load_lds(                      \
    (const __attribute__((address_space(1))) unsigned int*)(GP),               \
    (__attribute__((address_space(3))) unsigned int*)(LP), 16, 0, 0)

// counted vmcnt wait; all loop VMEM is global_load_lds (no dest VGPR), so the
// compiler inserts no waits of its own — this is the only vmcnt in the loop.
#define WAITVM(N) asm volatile("s_waitcnt vmcnt(" #N ")" ::: "memory")

// ---------------- Routing ----------------
__global__ __launch_bounds__(256) void k_route(
    const float* __restrict__ x, const float* __restrict__ gw,
    const float* __restrict__ bias, int* __restrict__ cnt,
    int* __restrict__ tok, float* __restrict__ wl, int* __restrict__ tslot)
{
    int t = blockIdx.x;
    int tid = threadIdx.x;
    int e2 = (tid & 15) * 2;
    int c  = tid >> 4;
    const float* xr = x + (size_t)t * HD;

    float a0 = 0.f, a1 = 0.f;
    int h0 = c * (HD / 16);
#pragma unroll 8
    for (int h = h0; h < h0 + HD / 16; ++h) {
        float xv = xr[h];
        float2 wv = *(const float2*)&gw[(size_t)h * NE + e2];
        a0 += xv * wv.x;
        a1 += xv * wv.y;
    }

    __shared__ float part[16][NE];
    part[c][e2]     = a0;
    part[c][e2 + 1] = a1;
    __syncthreads();

    __shared__ float sc[NE], sfc[NE];
    if (tid < NE) {
        float s = 0.f;
#pragma unroll
        for (int cc = 0; cc < 16; ++cc) s += part[cc][tid];
        float sig = 1.f / (1.f + expf(-s));
        sc[tid]  = sig;
        sfc[tid] = sig + bias[tid];
    }
    __syncthreads();

    if (tid == 0) {
        float gs[NGRP];
        for (int g = 0; g < NGRP; ++g) {
            float m1 = -3.0e38f, m2 = -3.0e38f;
            for (int j = 0; j < 4; ++j) {
                float v = sfc[4 * g + j];
                if (v > m1) { m2 = m1; m1 = v; } else if (v > m2) m2 = v;
            }
            gs[g] = m1 + m2;
        }
        bool gsel[NGRP];
        for (int g = 0; g < NGRP; ++g) gsel[g] = false;
        for (int r = 0; r < TKG; ++r) {
            int bi = -1; float bv = -3.0e38f;
            for (int g = 0; g < NGRP; ++g)
                if (!gsel[g] && gs[g] > bv) { bv = gs[g]; bi = g; }
            gsel[bi] = true;
        }
        float masked[NE];
        for (int i = 0; i < NE; ++i) masked[i] = gsel[i >> 2] ? sfc[i] : 0.0f;
        int   idx[TOPK]; float wv[TOPK]; float wsum = 0.f;
        for (int r = 0; r < TOPK; ++r) {
            int bi = -1; float bv = -3.0e38f;
            for (int i = 0; i < NE; ++i)
                if (masked[i] > bv) { bv = masked[i]; bi = i; }
            masked[bi] = -3.0e38f;
            idx[r] = bi; wv[r] = sc[bi]; wsum += wv[r];
        }
        float inv = RSCALE / (wsum + 1e-20f);
        for (int r = 0; r < TOPK; ++r) {
            int ee = idx[r];
            int pos = atomicAdd(&cnt[ee], 1);
            tok[(size_t)ee * TT + pos] = t;
            wl [(size_t)ee * TT + pos] = wv[r] * inv;
            tslot[t * TOPK + r] = ee * TT + pos;
        }
    }
}

// ---------------- Pack: gather x rows into MFMA-A-fragment slabs ----------------
// Block 0 also computes the prefix offsets (saves the k_offs launch).
__global__ __launch_bounds__(256) void k_pack(
    const float* __restrict__ x, const int* __restrict__ cnt,
    const int* __restrict__ tok, _Float16* __restrict__ Xe,
    int* __restrict__ offs)
{
    int bid  = blockIdx.x;
    int tid  = threadIdx.x;
    if (bid == 0 && tid == 0) {
        int s = 0;
        for (int e = 0; e < NE; ++e) { offs[e] = s; s += cnt[e]; }
    }
    int xcd  = bid & 7;
    int slot = bid >> 3;            // 0..127
    int e    = xcd * 4 + (slot & 3);
    int s    = slot >> 2;           // 0..31
    int n_e = cnt[e];
    if (n_e == 0) return;
    int w = tid >> 6, lane = tid & 63;
    int m16 = lane & 15, q = lane >> 4;
    _Float16* base = Xe + ((size_t)e * NSX + s) * SLAB;
#pragma unroll
    for (int k = 0; k < 4; ++k) {
        int mt = w + k * 4;
        int slot2 = mt * 16 + m16;
        if (slot2 >= n_e) slot2 = n_e - 1;   // clamp: dup of last row (finite garbage)
        int t = tok[e * TT + slot2];
        const float* src = x + (size_t)t * HD + s * 32 + q * 8;
        f32x4 v0 = *(const f32x4*)src;
        f32x4 v1 = *(const f32x4*)(src + 4);
        half8 h;
        h[0] = (_Float16)v0.x; h[1] = (_Float16)v0.y; h[2] = (_Float16)v0.z; h[3] = (_Float16)v0.w;
        h[4] = (_Float16)v1.x; h[5] = (_Float16)v1.y; h[6] = (_Float16)v1.z; h[7] = (_Float16)v1.w;
        *(half8*)(base + ((size_t)mt * 64 + lane) * 8) = h;
    }
}

// ---------------- Gate/Up ----------------
// 2048 blocks (XCD-swizzled: expert e on XCD e>>2), 128 threads = 2 waves.
// Block tile: 128 tokens x 16 cols; wave w owns mts [4w,4w+4). Small 36 KB
// blocks -> 4 blocks/CU = 8 waves/CU: four independent counted-vmcnt pipelines
// per CU (cross-block TLP hides what depth alone cannot). Per step: wave0
// stages G-tile (2 gloads), wave1 U-tile (2), each wave its own A-half (4).
// NBUF=3, stage 2 ahead, two barriers per step (bar A frees the buffer,
// bar B publishes data after each wave's own counted WAITVM).
// W content swizzle: LDS[r][c] = W[r][c ^ ((r>>3 & 3)<<2)].
__global__ __launch_bounds__(128, 1) void k_gateup(
    const _Float16* __restrict__ Xe, const float* __restrict__ Wg,
    const float* __restrict__ Wu, const int* __restrict__ cnt,
    _Float16* __restrict__ A)
{
    int bid  = blockIdx.x;
    int xcd  = bid & 7;
    int slot = bid >> 3;            // 0..255
    int e    = xcd * 4 + (slot & 3);
    int rest = slot >> 2;           // 0..63
    int ig    = rest & 31;          // 16-col group 0..31
    int ttile = rest >> 5;
    int n_e = cnt[e];
    if (ttile * 128 >= n_e) return;
    int mtbase = ttile * 8;
    int i0 = ig * 16;
    int tid  = threadIdx.x;
    int w    = tid >> 6;            // wave 0/1 -> mts [4w, 4w+4)
    int lane = tid & 63;
    int m16 = lane & 15, q = lane >> 4;

    __shared__ __align__(16) float    LG[3][32][16];   // 6 KB
    __shared__ __align__(16) float    LU[3][32][16];   // 6 KB
    __shared__ __align__(16) _Float16 LA[3][4096];     // 24 KB

    const _Float16* aslab = Xe + (size_t)e * NSX * SLAB + (size_t)mtbase * 512;
    const float* gw0 = Wg + (size_t)e * HD * IDIM + i0;
    const float* uw0 = Wu + (size_t)e * HD * IDIM + i0;

    f32x4 accG[4], accU[4];
#pragma unroll
    for (int mt = 0; mt < 4; ++mt) {
        accG[mt] = (f32x4){0.f, 0.f, 0.f, 0.f};
        accU[mt] = (f32x4){0.f, 0.f, 0.f, 0.f};
    }

    // per-wave 6 gloads/step: 2 weight (wave0->G, wave1->U) + 4 A (own half).
    // weight gload i covers rows 16i..16i+15: lane l -> row 16i+(l>>2),
    // src col = ((l&3)<<2) ^ ((row>>3 & 3)<<2)  (pre-swizzled source).
#define GU_STAGE(B, KS)                                                        \
    { const float* wp_ = (w == 0) ? gw0 : uw0;                                 \
      float* lp_ = (w == 0) ? &LG[B][0][0] : &LU[B][0][0];                     \
      _Pragma("unroll")                                                        \
      for (int i_ = 0; i_ < 2; ++i_) {                                         \
        int row_  = i_ * 16 + (lane >> 2);                                     \
        int csrc_ = ((lane & 3) << 2) ^ (((row_ >> 3) & 3) << 2);              \
        GLOAD16(wp_ + ((size_t)(KS) * 32 + row_) * IDIM + csrc_,               \
                lp_ + i_ * 256);                                               \
      }                                                                        \
      _Pragma("unroll")                                                        \
      for (int i_ = 0; i_ < 4; ++i_) {                                         \
        int off_ = (w * 4 + i_) * 512;                                         \
        GLOAD16(aslab + (size_t)(KS) * SLAB + off_ + lane * 8, &LA[B][off_]);  \
      } }

    // frag reads: lane (m16,q) needs W[k=q*8+j][i0+m16] at stored col
    // m16 ^ (q<<2); A via contiguous b128.
#define GU_COMPUTE(B)                                                          \
    { int lc = m16 ^ (q << 2);                                                 \
      half8 bg, bu;                                                            \
      _Pragma("unroll")                                                        \
      for (int j_ = 0; j_ < 8; ++j_) {                                         \
        bg[j_] = (_Float16)LG[B][q * 8 + j_][lc];                              \
        bu[j_] = (_Float16)LU[B][q * 8 + j_][lc];                              \
      }                                                                        \
      __builtin_amdgcn_s_setprio(1);                                           \
      _Pragma("unroll")                                                        \
      for (int mt_ = 0; mt_ < 4; ++mt_) {                                      \
        half8 afr = *(const half8*)&LA[B][(w * 4 + mt_) * 512 + lane * 8];     \
        accG[mt_] = __builtin_amdgcn_mfma_f32_16x16x32_f16(afr, bg, accG[mt_], 0, 0, 0); \
        accU[mt_] = __builtin_amdgcn_mfma_f32_16x16x32_f16(afr, bu, accU[mt_], 0, 0, 0); \
      }                                                                        \
      __builtin_amdgcn_s_setprio(0); }

    constexpr int NK = HD / 32;   // 32
    GU_STAGE(0, 0) GU_STAGE(1, 1)

#pragma unroll
    for (int ks = 0; ks < NK; ++ks) {
        __builtin_amdgcn_s_barrier();            // buffer (ks+2)%3 now free
        if (ks + 2 < NK) GU_STAGE((ks + 2) % 3, ks + 2)
        if      (ks + 2 < NK)  { WAITVM(12); }   // keep 2 steps in flight
        else if (ks + 1 < NK)  { WAITVM(6);  }
        else                   { WAITVM(0);  }
        __builtin_amdgcn_s_barrier();            // step-ks data published
        __builtin_amdgcn_sched_barrier(0);
        GU_COMPUTE(ks % 3)
    }
#undef GU_STAGE
#undef GU_COMPUTE

    // store silu(g)*u into A in A-fragment slab order (for k_down's A-operand)
    int iyw = ig;                               // 16-col tile index 0..31
    _Float16* aout = A + ((size_t)e * NSA + (iyw >> 1)) * SLAB;
    int cj   = m16 & 7;
    int lsub = ((iyw * 2 + (m16 >> 3)) & 3) * 16;
#pragma unroll
    for (int mt = 0; mt < 4; ++mt) {
#pragma unroll
        for (int r = 0; r < 4; ++r) {
            float g = accG[mt][r], u = accU[mt][r];
            float a = (g / (1.f + expf(-g))) * u;
            int lp = (q * 4 + r) + lsub;
            aout[((size_t)(mtbase + w * 4 + mt) * 64 + lp) * 8 + cj] = (_Float16)a;
        }
    }
}

// ---------------- Down ----------------
// 4096 blocks (XCD-swizzled), 128 threads = 2 waves; tile 128 tokens x 16 cols.
// Same structure (30 KB/block -> 5 blocks/CU). Per step per wave: 1 weight
// gload (wave w -> rows 16w..16w+15) + 4 A gloads = 5.
__global__ __launch_bounds__(128, 1) void k_down(
    const _Float16* __restrict__ A, const float* __restrict__ Wd,
    const int* __restrict__ cnt, const int* __restrict__ offs,
    const float* __restrict__ wl, float* __restrict__ Y)
{
    int bid  = blockIdx.x;
    int xcd  = bid & 7;
    int slot = bid >> 3;            // 0..511
    int e    = xcd * 4 + (slot & 3);
    int rest = slot >> 2;           // 0..127
    int hg    = rest & 63;          // 16-col group 0..63
    int ttile = rest >> 6;
    int n_e = cnt[e];
    if (ttile * 128 >= n_e) return;
    int mtbase = ttile * 8;
    int h0 = hg * 16;
    int tid  = threadIdx.x;
    int w    = tid >> 6;
    int lane = tid & 63;
    int m16 = lane & 15, q = lane >> 4;

    __shared__ __align__(16) float    LD[3][32][16];   // 6 KB
    __shared__ __align__(16) _Float16 LA[3][4096];     // 24 KB

    const _Float16* aslab = A + (size_t)e * NSA * SLAB + (size_t)mtbase * 512;
    const float* dw0 = Wd + (size_t)e * IDIM * HD + h0;

    f32x4 acc[4];
#pragma unroll
    for (int mt = 0; mt < 4; ++mt) acc[mt] = (f32x4){0.f, 0.f, 0.f, 0.f};

#define DN_STAGE(B, KS)                                                        \
    { int row_  = w * 16 + (lane >> 2);                                        \
      int csrc_ = ((lane & 3) << 2) ^ (((row_ >> 3) & 3) << 2);                \
      GLOAD16(dw0 + ((size_t)(KS) * 32 + row_) * HD + csrc_,                   \
              &LD[B][w * 16][0]);                                              \
      _Pragma("unroll")                                                        \
      for (int i_ = 0; i_ < 4; ++i_) {                                         \
        int off_ = (w * 4 + i_) * 512;                                         \
        GLOAD16(aslab + (size_t)(KS) * SLAB + off_ + lane * 8, &LA[B][off_]);  \
      } }

#define DN_COMPUTE(B)                                                          \
    { int lc = m16 ^ (q << 2);                                                 \
      half8 bd;                                                                \
      _Pragma("unroll")                                                        \
      for (int j_ = 0; j_ < 8; ++j_) bd[j_] = (_Float16)LD[B][q * 8 + j_][lc]; \
      __builtin_amdgcn_s_setprio(1);                                           \
      _Pragma("unroll")                                                        \
      for (int mt_ = 0; mt_ < 4; ++mt_) {                                      \
        half8 afr = *(const half8*)&LA[B][(w * 4 + mt_) * 512 + lane * 8];     \
        acc[mt_] = __builtin_amdgcn_mfma_f32_16x16x32_f16(afr, bd, acc[mt_], 0, 0, 0); \
      }                                                                        \
      __builtin_amdgcn_s_setprio(0); }

    constexpr int NK = IDIM / 32;  // 16
    DN_STAGE(0, 0) DN_STAGE(1, 1)

#pragma unroll
    for (int ks = 0; ks < NK; ++ks) {
        __builtin_amdgcn_s_barrier();
        if (ks + 2 < NK) DN_STAGE((ks + 2) % 3, ks + 2)
        if      (ks + 2 < NK)  { WAITVM(10); }
        else if (ks + 1 < NK)  { WAITVM(5);  }
        else                   { WAITVM(0);  }
        __builtin_amdgcn_s_barrier();
        __builtin_amdgcn_sched_barrier(0);
        DN_COMPUTE(ks % 3)
    }
#undef DN_STAGE
#undef DN_COMPUTE

    int oe = offs[e];
    int col = h0 + m16;
#pragma unroll
    for (int mt = 0; mt < 4; ++mt) {
#pragma unroll
        for (int r = 0; r < 4; ++r) {
            int slot2 = ttile * 128 + (w * 4 + mt) * 16 + q * 4 + r;
            if (slot2 < n_e) {
                float wt = wl[(size_t)e * TT + slot2];
                Y[(size_t)(oe + slot2) * HD + col] = wt * acc[mt][r];
            }
        }
    }
}

// ---------------- Combine: out[t] = sum of the token's 8 weighted partials ----
__global__ __launch_bounds__(256) void k_combine(
    const float* __restrict__ Y, const int* __restrict__ tslot,
    const int* __restrict__ offs, float* __restrict__ out)
{
    int t = blockIdx.x, tid = threadIdx.x;
    f32x4 s = (f32x4){0.f, 0.f, 0.f, 0.f};
#pragma unroll
    for (int r = 0; r < TOPK; ++r) {
        int ts  = tslot[t * TOPK + r];
        int e   = ts >> 8;            // TT = 256
        int pos = ts & 255;
        const float* yp = Y + (size_t)(offs[e] + pos) * HD + tid * 4;
        f32x4 v = *(const f32x4*)yp;
        s.x += v.x; s.y += v.y; s.z += v.z; s.w += v.w;
    }
    *(f32x4*)&out[(size_t)t * HD + tid * 4] = s;
}

extern "C" void kernel_launch(void* const* d_in, const int* in_sizes, int n_in,
                              void* d_out, int out_size, void* d_ws, size_t ws_size,
                              hipStream_t stream) {
    const float* x    = (const float*)d_in[0];
    const float* gw   = (const float*)d_in[1];
    const float* bias = (const float*)d_in[2];
    const float* Wg   = (const float*)d_in[3];
    const float* Wu   = (const float*)d_in[4];
    const float* Wd   = (const float*)d_in[5];
    float* out = (float*)d_out;   // reference output dtype is float32

    char* ws = (char*)d_ws;
    int*      cnt   = (int*)(ws + WS_CNT);
    int*      tok   = (int*)(ws + WS_TOK);
    float*    wl    = (float*)(ws + WS_WL);
    int*      tslot = (int*)(ws + WS_TSLOT);
    int*      offs  = (int*)(ws + WS_OFFS);
    _Float16* Xe    = (_Float16*)(ws + WS_XE);
    _Float16* A     = (_Float16*)(ws + WS_A);
    float*    Y     = (float*)(ws + WS_XE);   // aliases Xe (dead after k_gateup)

    hipMemsetAsync(ws, 0, 256, stream);       // expert counters

    k_route<<<TT, 256, 0, stream>>>(x, gw, bias, cnt, tok, wl, tslot);
    k_pack<<<NE * NSX, 256, 0, stream>>>(x, cnt, tok, Xe, offs);
    k_gateup<<<NE * 2 * (IDIM / 16), 128, 0, stream>>>(Xe, Wg, Wu, cnt, A);
    k_down<<<NE * 2 * (HD / 16), 128, 0, stream>>>(A, Wd, cnt, offs, wl, Y);
    k_combine<<<TT, 256, 0, stream>>>(Y, tslot, offs, out);
}

// Round 7
// 246.263 us; speedup vs baseline: 1.0843x; 1.0843x over previous
//
#include <hip/hip_runtime.h>
#include <cstdint>
#include <cmath>

// Problem constants
constexpr int TT   = 256;   // tokens
constexpr int HD   = 1024;  // hidden
constexpr int IDIM = 512;   // intermediate
constexpr int NE   = 32;    // experts
constexpr int NGRP = 8;
constexpr int TKG  = 4;
constexpr int TOPK = 8;
constexpr float RSCALE = 2.5f;

constexpr int NSX  = HD / 32;     // 32 k-slabs in Xe
constexpr int NSA  = IDIM / 32;   // 16 k-slabs in A
constexpr int SLAB = 16 * 64 * 8; // halves per (expert, slab): 16 mt-tiles x 64 lanes x 8

typedef float    f32x4 __attribute__((ext_vector_type(4)));
typedef _Float16 half8 __attribute__((ext_vector_type(8)));

// Workspace layout (bytes)
constexpr size_t WS_CNT   = 0;                                 // NE ints (zeroed)
constexpr size_t WS_TOK   = 256;                               // NE*TT ints
constexpr size_t WS_WL    = WS_TOK   + (size_t)NE * TT * 4;    // NE*TT floats
constexpr size_t WS_TSLOT = WS_WL    + (size_t)NE * TT * 4;    // TT*TOPK ints
constexpr size_t WS_OFFS  = WS_TSLOT + (size_t)TT * TOPK * 4;  // NE ints (pad 256)
constexpr size_t WS_XE    = WS_OFFS  + 256;                    // 16 MB Xe; Y aliases this after gateup
constexpr size_t WS_A     = WS_XE + (size_t)NE * NSX * SLAB * 2; // 8 MB A
// Y = f32[2048][HD] at WS_XE (8 MB <= 16 MB Xe region, Xe dead after k_gateup)

// global->LDS direct staging, 16B per lane (dest = wave-uniform base + lane*16)
#define GLOAD16(GP, LP) __builtin_amdgcn_global_load_lds(                      \
    (const __attribute__((address_space(1))) unsigned int*)(GP),               \
    (__attribute__((address_space(3))) unsigned int*)(LP), 16, 0, 0)

// counted vmcnt wait; all loop VMEM is global_load_lds (no dest VGPR), so the
// compiler inserts no waits of its own — this is the only vmcnt in the loop.
#define WAITVM(N) asm volatile("s_waitcnt vmcnt(" #N ")" ::: "memory")

// ---------------- Routing ----------------
__global__ __launch_bounds__(256) void k_route(
    const float* __restrict__ x, const float* __restrict__ gw,
    const float* __restrict__ bias, int* __restrict__ cnt,
    int* __restrict__ tok, float* __restrict__ wl, int* __restrict__ tslot)
{
    int t = blockIdx.x;
    int tid = threadIdx.x;
    int e2 = (tid & 15) * 2;
    int c  = tid >> 4;
    const float* xr = x + (size_t)t * HD;

    float a0 = 0.f, a1 = 0.f;
    int h0 = c * (HD / 16);
#pragma unroll 8
    for (int h = h0; h < h0 + HD / 16; ++h) {
        float xv = xr[h];
        float2 wv = *(const float2*)&gw[(size_t)h * NE + e2];
        a0 += xv * wv.x;
        a1 += xv * wv.y;
    }

    __shared__ float part[16][NE];
    part[c][e2]     = a0;
    part[c][e2 + 1] = a1;
    __syncthreads();

    __shared__ float sc[NE], sfc[NE];
    if (tid < NE) {
        float s = 0.f;
#pragma unroll
        for (int cc = 0; cc < 16; ++cc) s += part[cc][tid];
        float sig = 1.f / (1.f + expf(-s));
        sc[tid]  = sig;
        sfc[tid] = sig + bias[tid];
    }
    __syncthreads();

    if (tid == 0) {
        float gs[NGRP];
        for (int g = 0; g < NGRP; ++g) {
            float m1 = -3.0e38f, m2 = -3.0e38f;
            for (int j = 0; j < 4; ++j) {
                float v = sfc[4 * g + j];
                if (v > m1) { m2 = m1; m1 = v; } else if (v > m2) m2 = v;
            }
            gs[g] = m1 + m2;
        }
        bool gsel[NGRP];
        for (int g = 0; g < NGRP; ++g) gsel[g] = false;
        for (int r = 0; r < TKG; ++r) {
            int bi = -1; float bv = -3.0e38f;
            for (int g = 0; g < NGRP; ++g)
                if (!gsel[g] && gs[g] > bv) { bv = gs[g]; bi = g; }
            gsel[bi] = true;
        }
        float masked[NE];
        for (int i = 0; i < NE; ++i) masked[i] = gsel[i >> 2] ? sfc[i] : 0.0f;
        int   idx[TOPK]; float wv[TOPK]; float wsum = 0.f;
        for (int r = 0; r < TOPK; ++r) {
            int bi = -1; float bv = -3.0e38f;
            for (int i = 0; i < NE; ++i)
                if (masked[i] > bv) { bv = masked[i]; bi = i; }
            masked[bi] = -3.0e38f;
            idx[r] = bi; wv[r] = sc[bi]; wsum += wv[r];
        }
        float inv = RSCALE / (wsum + 1e-20f);
        for (int r = 0; r < TOPK; ++r) {
            int ee = idx[r];
            int pos = atomicAdd(&cnt[ee], 1);
            tok[(size_t)ee * TT + pos] = t;
            wl [(size_t)ee * TT + pos] = wv[r] * inv;
            tslot[t * TOPK + r] = ee * TT + pos;
        }
    }
}

// ---------------- Pack: gather x rows into MFMA-A-fragment slabs ----------------
// Block 0 also computes the prefix offsets (saves a launch).
__global__ __launch_bounds__(256) void k_pack(
    const float* __restrict__ x, const int* __restrict__ cnt,
    const int* __restrict__ tok, _Float16* __restrict__ Xe,
    int* __restrict__ offs)
{
    int bid  = blockIdx.x;
    int tid  = threadIdx.x;
    if (bid == 0 && tid == 0) {
        int s = 0;
        for (int e = 0; e < NE; ++e) { offs[e] = s; s += cnt[e]; }
    }
    int xcd  = bid & 7;
    int slot = bid >> 3;            // 0..127
    int e    = xcd * 4 + (slot & 3);
    int s    = slot >> 2;           // 0..31
    int n_e = cnt[e];
    if (n_e == 0) return;
    int w = tid >> 6, lane = tid & 63;
    int m16 = lane & 15, q = lane >> 4;
    _Float16* base = Xe + ((size_t)e * NSX + s) * SLAB;
#pragma unroll
    for (int k = 0; k < 4; ++k) {
        int mt = w + k * 4;
        int slot2 = mt * 16 + m16;
        if (slot2 >= n_e) slot2 = n_e - 1;   // clamp: dup of last row (finite garbage)
        int t = tok[e * TT + slot2];
        const float* src = x + (size_t)t * HD + s * 32 + q * 8;
        f32x4 v0 = *(const f32x4*)src;
        f32x4 v1 = *(const f32x4*)(src + 4);
        half8 h;
        h[0] = (_Float16)v0.x; h[1] = (_Float16)v0.y; h[2] = (_Float16)v0.z; h[3] = (_Float16)v0.w;
        h[4] = (_Float16)v1.x; h[5] = (_Float16)v1.y; h[6] = (_Float16)v1.z; h[7] = (_Float16)v1.w;
        *(half8*)(base + ((size_t)mt * 64 + lane) * 8) = h;
    }
}

// ---------------- Gate/Up ----------------
// 512 blocks (XCD-swizzled: expert e on XCD e>>2), 512 threads = 8 waves.
// Block tile: 128 tokens x 64 cols. Wave w: wr=w&3 owns mts {wr, wr+4};
// wc=w>>2 owns 32-col half. Per step each wave stages exactly 3 gloads
// (A chunk w, G chunk w, U chunk w); NBUF=4, depth-3, counted vmcnt
// (steady WAITVM(9) = 3 stages x 3 loads in flight; never 0 in loop).
// W stored [32][64] f32; per-32-col-group XOR by ((k>>3)&1)<<4 (pre-swizzled
// source) makes the B-frag b32 reads 2-way (free): (k>>3)&1 == q&1.
__global__ __launch_bounds__(512, 1) void k_gateup(
    const _Float16* __restrict__ Xe, const float* __restrict__ Wg,
    const float* __restrict__ Wu, const int* __restrict__ cnt,
    _Float16* __restrict__ A)
{
    int bid  = blockIdx.x;
    int xcd  = bid & 7;
    int slot = bid >> 3;            // 0..63
    int e    = xcd * 4 + (slot & 3);
    int rest = slot >> 2;           // 0..15
    int ig   = rest & 7;            // 64-col group 0..7
    int tt   = rest >> 3;           // token tile 0..1
    int n_e = cnt[e];
    if (tt * 128 >= n_e) return;
    int mtbase = tt * 8;
    int tid  = threadIdx.x;
    int w    = tid >> 6;            // wave 0..7
    int lane = tid & 63;
    int m16 = lane & 15, q = lane >> 4;
    int wr = w & 3, wc = w >> 2;

    __shared__ __align__(16) float    LG[4][32][64];   // 32 KB
    __shared__ __align__(16) float    LU[4][32][64];   // 32 KB
    __shared__ __align__(16) _Float16 LA[4][4096];     // 32 KB

    // this wave's staging sources
    const _Float16* asrc = Xe + (size_t)e * NSX * SLAB + (size_t)(mtbase + w) * 512 + lane * 8;
    const float* gp = Wg + (size_t)e * HD * IDIM + ig * 64;
    const float* up = Wu + (size_t)e * HD * IDIM + ig * 64;
    int wrow  = 4 * w + (lane >> 4);                       // W chunk w: rows 4w..4w+3
    int wcsrc = ((lane & 15) << 2) ^ (((w >> 1) & 1) << 4); // pre-swizzled source col

    f32x4 accG[2][2], accU[2][2];
#pragma unroll
    for (int a_ = 0; a_ < 2; ++a_)
#pragma unroll
        for (int b_ = 0; b_ < 2; ++b_) {
            accG[a_][b_] = (f32x4){0.f, 0.f, 0.f, 0.f};
            accU[a_][b_] = (f32x4){0.f, 0.f, 0.f, 0.f};
        }

#define GU_STAGE(B, KS)                                                        \
    { GLOAD16(asrc + (size_t)(KS) * SLAB, &LA[B][w * 512]);                    \
      GLOAD16(gp + ((size_t)(KS) * 32 + wrow) * IDIM + wcsrc, &LG[B][4 * w][0]); \
      GLOAD16(up + ((size_t)(KS) * 32 + wrow) * IDIM + wcsrc, &LU[B][4 * w][0]); }

#define GU_COMPUTE(B)                                                          \
    { int c0 = wc * 32 + (m16 ^ ((q & 1) << 4));                               \
      int c1 = wc * 32 + ((16 + m16) ^ ((q & 1) << 4));                        \
      half8 bg0, bg1, bu0, bu1;                                                \
      _Pragma("unroll")                                                        \
      for (int j_ = 0; j_ < 8; ++j_) {                                         \
        bg0[j_] = (_Float16)LG[B][q * 8 + j_][c0];                             \
        bg1[j_] = (_Float16)LG[B][q * 8 + j_][c1];                             \
        bu0[j_] = (_Float16)LU[B][q * 8 + j_][c0];                             \
        bu1[j_] = (_Float16)LU[B][q * 8 + j_][c1];                             \
      }                                                                        \
      half8 a0 = *(const half8*)&LA[B][wr * 512 + lane * 8];                   \
      half8 a1 = *(const half8*)&LA[B][(wr + 4) * 512 + lane * 8];             \
      __builtin_amdgcn_s_setprio(1);                                           \
      accG[0][0] = __builtin_amdgcn_mfma_f32_16x16x32_f16(a0, bg0, accG[0][0], 0, 0, 0); \
      accG[0][1] = __builtin_amdgcn_mfma_f32_16x16x32_f16(a0, bg1, accG[0][1], 0, 0, 0); \
      accU[0][0] = __builtin_amdgcn_mfma_f32_16x16x32_f16(a0, bu0, accU[0][0], 0, 0, 0); \
      accU[0][1] = __builtin_amdgcn_mfma_f32_16x16x32_f16(a0, bu1, accU[0][1], 0, 0, 0); \
      accG[1][0] = __builtin_amdgcn_mfma_f32_16x16x32_f16(a1, bg0, accG[1][0], 0, 0, 0); \
      accG[1][1] = __builtin_amdgcn_mfma_f32_16x16x32_f16(a1, bg1, accG[1][1], 0, 0, 0); \
      accU[1][0] = __builtin_amdgcn_mfma_f32_16x16x32_f16(a1, bu0, accU[1][0], 0, 0, 0); \
      accU[1][1] = __builtin_amdgcn_mfma_f32_16x16x32_f16(a1, bu1, accU[1][1], 0, 0, 0); \
      __builtin_amdgcn_s_setprio(0); }

    constexpr int NK = HD / 32;   // 32
    GU_STAGE(0, 0) GU_STAGE(1, 1) GU_STAGE(2, 2)

#pragma unroll
    for (int ks = 0; ks < NK; ++ks) {
        __builtin_amdgcn_s_barrier();            // all waves done reading buf (ks+3)&3
        if (ks + 3 < NK) GU_STAGE((ks + 3) & 3, ks + 3)
        if      (ks + 4 <= NK) { WAITVM(9); }    // stage ks complete (mine)
        else if (ks + 3 == NK) { WAITVM(6); }
        else if (ks + 2 == NK) { WAITVM(3); }
        else                   { WAITVM(0); }
        __builtin_amdgcn_s_barrier();            // stage ks complete (all waves)
        __builtin_amdgcn_sched_barrier(0);
        GU_COMPUTE(ks & 3)
    }
#undef GU_STAGE
#undef GU_COMPUTE

    // store silu(g)*u into A in A-fragment slab order (for k_down's A-operand)
    int sa = ig * 2 + wc;                        // IDIM k-slab 0..15
    _Float16* aout = A + ((size_t)e * NSA + sa) * SLAB;
    int jp = m16 & 7;
#pragma unroll
    for (int mtl = 0; mtl < 2; ++mtl) {
        int mtg = mtbase + wr + 4 * mtl;
#pragma unroll
        for (int cg = 0; cg < 2; ++cg) {
            int qp = cg * 2 + (m16 >> 3);
#pragma unroll
            for (int r = 0; r < 4; ++r) {
                float g = accG[mtl][cg][r], u = accU[mtl][cg][r];
                float a = (g / (1.f + expf(-g))) * u;
                int lanep = qp * 16 + q * 4 + r;
                aout[((size_t)mtg * 64 + lanep) * 8 + jp] = (_Float16)a;
            }
        }
    }
}

// ---------------- Down ----------------
// 512 blocks (XCD-swizzled), 512 threads = 8 waves; tile 128 tokens x 128 cols.
// Wave w: wr=w&3 -> mts {wr,wr+4}; wc=w>>2 -> 64-col half (4 cg). Per step per
// wave 3 gloads (A chunk w, W chunks {w, w+8}); same NBUF=4 depth-3 pipeline.
__global__ __launch_bounds__(512, 1) void k_down(
    const _Float16* __restrict__ A, const float* __restrict__ Wd,
    const int* __restrict__ cnt, const int* __restrict__ offs,
    const float* __restrict__ wl, float* __restrict__ Y)
{
    int bid  = blockIdx.x;
    int xcd  = bid & 7;
    int slot = bid >> 3;            // 0..63
    int e    = xcd * 4 + (slot & 3);
    int rest = slot >> 2;           // 0..15
    int hg   = rest & 7;            // 128-col group 0..7
    int tt   = rest >> 3;
    int n_e = cnt[e];
    if (tt * 128 >= n_e) return;
    int mtbase = tt * 8;
    int h0 = hg * 128;
    int tid  = threadIdx.x;
    int w    = tid >> 6;
    int lane = tid & 63;
    int m16 = lane & 15, q = lane >> 4;
    int wr = w & 3, wc = w >> 2;

    __shared__ __align__(16) float    LD[4][32][128];  // 64 KB
    __shared__ __align__(16) _Float16 LA[4][4096];     // 32 KB

    const _Float16* asrc = A + (size_t)e * NSA * SLAB + (size_t)(mtbase + w) * 512 + lane * 8;
    const float* dp = Wd + (size_t)e * IDIM * HD + h0;
    // W chunk c (1 KB = 2 rows x 128 cols): lane -> row 2c+(lane>>5),
    // source col pre-swizzled by ((c>>2)&1)<<4  ((k>>3) is constant per chunk).
    int rA = 2 * w + (lane >> 5);
    int rB = 2 * (w + 8) + (lane >> 5);
    int csA = ((lane & 31) << 2) ^ (((w >> 2) & 1) << 4);
    int csB = ((lane & 31) << 2) ^ ((((w + 8) >> 2) & 1) << 4);

    f32x4 acc[2][4];
#pragma unroll
    for (int a_ = 0; a_ < 2; ++a_)
#pragma unroll
        for (int b_ = 0; b_ < 4; ++b_) acc[a_][b_] = (f32x4){0.f, 0.f, 0.f, 0.f};

#define DN_STAGE(B, KS)                                                        \
    { GLOAD16(asrc + (size_t)(KS) * SLAB, &LA[B][w * 512]);                    \
      GLOAD16(dp + ((size_t)(KS) * 32 + rA) * HD + csA, &LD[B][2 * w][0]);     \
      GLOAD16(dp + ((size_t)(KS) * 32 + rB) * HD + csB, &LD[B][2 * (w + 8)][0]); }

#define DN_COMPUTE(B)                                                          \
    { half8 bd[4];                                                             \
      _Pragma("unroll")                                                        \
      for (int cg = 0; cg < 4; ++cg) {                                         \
        int col = (wc * 2 + (cg >> 1)) * 32 + ((((cg & 1) << 4) + m16) ^ ((q & 1) << 4)); \
        _Pragma("unroll")                                                      \
        for (int j_ = 0; j_ < 8; ++j_) bd[cg][j_] = (_Float16)LD[B][q * 8 + j_][col]; \
      }                                                                        \
      half8 a0 = *(const half8*)&LA[B][wr * 512 + lane * 8];                   \
      half8 a1 = *(const half8*)&LA[B][(wr + 4) * 512 + lane * 8];             \
      __builtin_amdgcn_s_setprio(1);                                           \
      _Pragma("unroll")                                                        \
      for (int cg = 0; cg < 4; ++cg) {                                         \
        acc[0][cg] = __builtin_amdgcn_mfma_f32_16x16x32_f16(a0, bd[cg], acc[0][cg], 0, 0, 0); \
        acc[1][cg] = __builtin_amdgcn_mfma_f32_16x16x32_f16(a1, bd[cg], acc[1][cg], 0, 0, 0); \
      }                                                                        \
      __builtin_amdgcn_s_setprio(0); }

    constexpr int NK = IDIM / 32;  // 16
    DN_STAGE(0, 0) DN_STAGE(1, 1) DN_STAGE(2, 2)

#pragma unroll
    for (int ks = 0; ks < NK; ++ks) {
        __builtin_amdgcn_s_barrier();
        if (ks + 3 < NK) DN_STAGE((ks + 3) & 3, ks + 3)
        if      (ks + 4 <= NK) { WAITVM(9); }
        else if (ks + 3 == NK) { WAITVM(6); }
        else if (ks + 2 == NK) { WAITVM(3); }
        else                   { WAITVM(0); }
        __builtin_amdgcn_s_barrier();
        __builtin_amdgcn_sched_barrier(0);
        DN_COMPUTE(ks & 3)
    }
#undef DN_STAGE
#undef DN_COMPUTE

    int oe = offs[e];
#pragma unroll
    for (int mtl = 0; mtl < 2; ++mtl) {
        int mtg = wr + 4 * mtl;
#pragma unroll
        for (int cg = 0; cg < 4; ++cg) {
            int col = h0 + wc * 64 + cg * 16 + m16;
#pragma unroll
            for (int r = 0; r < 4; ++r) {
                int slot2 = tt * 128 + mtg * 16 + q * 4 + r;
                if (slot2 < n_e) {
                    float wt = wl[(size_t)e * TT + slot2];
                    Y[(size_t)(oe + slot2) * HD + col] = wt * acc[mtl][cg][r];
                }
            }
        }
    }
}

// ---------------- Combine: out[t] = sum of the token's 8 weighted partials ----
__global__ __launch_bounds__(256) void k_combine(
    const float* __restrict__ Y, const int* __restrict__ tslot,
    const int* __restrict__ offs, float* __restrict__ out)
{
    int t = blockIdx.x, tid = threadIdx.x;
    f32x4 s = (f32x4){0.f, 0.f, 0.f, 0.f};
#pragma unroll
    for (int r = 0; r < TOPK; ++r) {
        int ts  = tslot[t * TOPK + r];
        int e   = ts >> 8;            // TT = 256
        int pos = ts & 255;
        const float* yp = Y + (size_t)(offs[e] + pos) * HD + tid * 4;
        f32x4 v = *(const f32x4*)yp;
        s.x += v.x; s.y += v.y; s.z += v.z; s.w += v.w;
    }
    *(f32x4*)&out[(size_t)t * HD + tid * 4] = s;
}

extern "C" void kernel_launch(void* const* d_in, const int* in_sizes, int n_in,
                              void* d_out, int out_size, void* d_ws, size_t ws_size,
                              hipStream_t stream) {
    const float* x    = (const float*)d_in[0];
    const float* gw   = (const float*)d_in[1];
    const float* bias = (const float*)d_in[2];
    const float* Wg   = (const float*)d_in[3];
    const float* Wu   = (const float*)d_in[4];
    const float* Wd   = (const float*)d_in[5];
    float* out = (float*)d_out;   // reference output dtype is float32

    char* ws = (char*)d_ws;
    int*      cnt   = (int*)(ws + WS_CNT);
    int*      tok   = (int*)(ws + WS_TOK);
    float*    wl    = (float*)(ws + WS_WL);
    int*      tslot = (int*)(ws + WS_TSLOT);
    int*      offs  = (int*)(ws + WS_OFFS);
    _Float16* Xe    = (_Float16*)(ws + WS_XE);
    _Float16* A     = (_Float16*)(ws + WS_A);
    float*    Y     = (float*)(ws + WS_XE);   // aliases Xe (dead after k_gateup)

    hipMemsetAsync(ws, 0, 256, stream);       // expert counters

    k_route<<<TT, 256, 0, stream>>>(x, gw, bias, cnt, tok, wl, tslot);
    k_pack<<<NE * NSX, 256, 0, stream>>>(x, cnt, tok, Xe, offs);
    k_gateup<<<512, 512, 0, stream>>>(Xe, Wg, Wu, cnt, A);
    k_down<<<512, 512, 0, stream>>>(A, Wd, cnt, offs, wl, Y);
    k_combine<<<TT, 256, 0, stream>>>(Y, tslot, offs, out);
}

// Round 8
// 246.010 us; speedup vs baseline: 1.0855x; 1.0010x over previous
//
#include <hip/hip_runtime.h>
#include <cstdint>
#include <cmath>

// Problem constants
constexpr int TT   = 256;   // tokens
constexpr int HD   = 1024;  // hidden
constexpr int IDIM = 512;   // intermediate
constexpr int NE   = 32;    // experts
constexpr int NGRP = 8;
constexpr int TKG  = 4;
constexpr int TOPK = 8;
constexpr float RSCALE = 2.5f;

constexpr int NSX  = HD / 32;     // 32 k-slabs in Xe
constexpr int NSA  = IDIM / 32;   // 16 k-slabs in A
constexpr int SLAB = 16 * 64 * 8; // halves per (expert, slab): 16 mt-tiles x 64 lanes x 8

typedef float    f32x4 __attribute__((ext_vector_type(4)));
typedef _Float16 half8 __attribute__((ext_vector_type(8)));

// Workspace layout (bytes)
constexpr size_t WS_CNT   = 0;                                 // NE ints (zeroed)
constexpr size_t WS_TOK   = 256;                               // NE*TT ints
constexpr size_t WS_WL    = WS_TOK   + (size_t)NE * TT * 4;    // NE*TT floats
constexpr size_t WS_TSLOT = WS_WL    + (size_t)NE * TT * 4;    // TT*TOPK ints
constexpr size_t WS_OFFS  = WS_TSLOT + (size_t)TT * TOPK * 4;  // NE ints (pad 256)
constexpr size_t WS_XE    = WS_OFFS  + 256;                    // 16 MB Xe; Y aliases this after gateup
constexpr size_t WS_A     = WS_XE + (size_t)NE * NSX * SLAB * 2; // 8 MB A
// Y = f32[2048][HD] at WS_XE (8 MB <= 16 MB Xe region, Xe dead after k_gateup)

// global->LDS direct staging, 16B per lane (dest = wave-uniform base + lane*16)
#define GLOAD16(GP, LP) __builtin_amdgcn_global_load_lds(                      \
    (const __attribute__((address_space(1))) unsigned int*)(GP),               \
    (__attribute__((address_space(3))) unsigned int*)(LP), 16, 0, 0)

// register-dest global load, invisible to the compiler waitcnt pass (no
// auto-drain): ordering/guarding is 100% the manual WAITVM ladder.
#define GLD128(DST, PTR) asm volatile("global_load_dwordx4 %0, %1, off"       \
    : "=&v"(DST) : "v"(PTR) : "memory")
// LDS write of an f32x4 (addr = addrspace(3) pointer)
#define DSW128(LP, V) asm volatile("ds_write_b128 %0, %1"                     \
    :: "v"((__attribute__((address_space(3))) float*)(LP)), "v"(V) : "memory")

#define WAITVM(N) asm volatile("s_waitcnt vmcnt(" #N ")" ::: "memory")
#define LGKM0     asm volatile("s_waitcnt lgkmcnt(0)" ::: "memory")

// ---------------- Routing ----------------
__global__ __launch_bounds__(256) void k_route(
    const float* __restrict__ x, const float* __restrict__ gw,
    const float* __restrict__ bias, int* __restrict__ cnt,
    int* __restrict__ tok, float* __restrict__ wl, int* __restrict__ tslot)
{
    int t = blockIdx.x;
    int tid = threadIdx.x;
    int e2 = (tid & 15) * 2;
    int c  = tid >> 4;
    const float* xr = x + (size_t)t * HD;

    float a0 = 0.f, a1 = 0.f;
    int h0 = c * (HD / 16);
#pragma unroll 8
    for (int h = h0; h < h0 + HD / 16; ++h) {
        float xv = xr[h];
        float2 wv = *(const float2*)&gw[(size_t)h * NE + e2];
        a0 += xv * wv.x;
        a1 += xv * wv.y;
    }

    __shared__ float part[16][NE];
    part[c][e2]     = a0;
    part[c][e2 + 1] = a1;
    __syncthreads();

    __shared__ float sc[NE], sfc[NE];
    if (tid < NE) {
        float s = 0.f;
#pragma unroll
        for (int cc = 0; cc < 16; ++cc) s += part[cc][tid];
        float sig = 1.f / (1.f + expf(-s));
        sc[tid]  = sig;
        sfc[tid] = sig + bias[tid];
    }
    __syncthreads();

    if (tid == 0) {
        float gs[NGRP];
        for (int g = 0; g < NGRP; ++g) {
            float m1 = -3.0e38f, m2 = -3.0e38f;
            for (int j = 0; j < 4; ++j) {
                float v = sfc[4 * g + j];
                if (v > m1) { m2 = m1; m1 = v; } else if (v > m2) m2 = v;
            }
            gs[g] = m1 + m2;
        }
        bool gsel[NGRP];
        for (int g = 0; g < NGRP; ++g) gsel[g] = false;
        for (int r = 0; r < TKG; ++r) {
            int bi = -1; float bv = -3.0e38f;
            for (int g = 0; g < NGRP; ++g)
                if (!gsel[g] && gs[g] > bv) { bv = gs[g]; bi = g; }
            gsel[bi] = true;
        }
        float masked[NE];
        for (int i = 0; i < NE; ++i) masked[i] = gsel[i >> 2] ? sfc[i] : 0.0f;
        int   idx[TOPK]; float wv[TOPK]; float wsum = 0.f;
        for (int r = 0; r < TOPK; ++r) {
            int bi = -1; float bv = -3.0e38f;
            for (int i = 0; i < NE; ++i)
                if (masked[i] > bv) { bv = masked[i]; bi = i; }
            masked[bi] = -3.0e38f;
            idx[r] = bi; wv[r] = sc[bi]; wsum += wv[r];
        }
        float inv = RSCALE / (wsum + 1e-20f);
        for (int r = 0; r < TOPK; ++r) {
            int ee = idx[r];
            int pos = atomicAdd(&cnt[ee], 1);
            tok[(size_t)ee * TT + pos] = t;
            wl [(size_t)ee * TT + pos] = wv[r] * inv;
            tslot[t * TOPK + r] = ee * TT + pos;
        }
    }
}

// ---------------- Pack: gather x rows into MFMA-A-fragment slabs ----------------
// Block 0 also computes the prefix offsets (saves a launch).
__global__ __launch_bounds__(256) void k_pack(
    const float* __restrict__ x, const int* __restrict__ cnt,
    const int* __restrict__ tok, _Float16* __restrict__ Xe,
    int* __restrict__ offs)
{
    int bid  = blockIdx.x;
    int tid  = threadIdx.x;
    if (bid == 0 && tid == 0) {
        int s = 0;
        for (int e = 0; e < NE; ++e) { offs[e] = s; s += cnt[e]; }
    }
    int xcd  = bid & 7;
    int slot = bid >> 3;            // 0..127
    int e    = xcd * 4 + (slot & 3);
    int s    = slot >> 2;           // 0..31
    int n_e = cnt[e];
    if (n_e == 0) return;
    int w = tid >> 6, lane = tid & 63;
    int m16 = lane & 15, q = lane >> 4;
    _Float16* base = Xe + ((size_t)e * NSX + s) * SLAB;
#pragma unroll
    for (int k = 0; k < 4; ++k) {
        int mt = w + k * 4;
        int slot2 = mt * 16 + m16;
        if (slot2 >= n_e) slot2 = n_e - 1;   // clamp: dup of last row (finite garbage)
        int t = tok[e * TT + slot2];
        const float* src = x + (size_t)t * HD + s * 32 + q * 8;
        f32x4 v0 = *(const f32x4*)src;
        f32x4 v1 = *(const f32x4*)(src + 4);
        half8 h;
        h[0] = (_Float16)v0.x; h[1] = (_Float16)v0.y; h[2] = (_Float16)v0.z; h[3] = (_Float16)v0.w;
        h[4] = (_Float16)v1.x; h[5] = (_Float16)v1.y; h[6] = (_Float16)v1.z; h[7] = (_Float16)v1.w;
        *(half8*)(base + ((size_t)mt * 64 + lane) * 8) = h;
    }
}

// ---------------- Gate/Up ----------------
// 512 blocks (XCD-swizzled), 512 threads = 8 waves; tile 128 tok x 64 cols.
// HYBRID staging A/B experiment: A-chunks (L2-hit) via global_load_lds
// (counted); W-chunks (L2-miss) via asm register loads 3 steps deep, then asm
// ds_write into PADDED LDS ([32][66] f32: stride 66 => frag b32 reads are
// 2-way bank-free, write b128 at conflict floor). Window-robust vmcnt ladder
// counts both streams (3 vmem/wave/step: 2 W + 1 A; steady WAITVM(6)).
__global__ __launch_bounds__(512, 1) void k_gateup(
    const _Float16* __restrict__ Xe, const float* __restrict__ Wg,
    const float* __restrict__ Wu, const int* __restrict__ cnt,
    _Float16* __restrict__ A)
{
    int bid  = blockIdx.x;
    int xcd  = bid & 7;
    int slot = bid >> 3;            // 0..63
    int e    = xcd * 4 + (slot & 3);
    int rest = slot >> 2;           // 0..15
    int ig   = rest & 7;            // 64-col group 0..7
    int tt   = rest >> 3;           // token tile 0..1
    int n_e = cnt[e];
    if (tt * 128 >= n_e) return;
    int mtbase = tt * 8;
    int tid  = threadIdx.x;
    int w    = tid >> 6;            // wave 0..7
    int lane = tid & 63;
    int m16 = lane & 15, q = lane >> 4;
    int wr = w & 3, wc = w >> 2;

    __shared__ __align__(16) float    LG[4][32][66];   // 33.8 KB (pad 64->66)
    __shared__ __align__(16) float    LU[4][32][66];   // 33.8 KB
    __shared__ __align__(16) _Float16 LA[4][4096];     // 32 KB

    const _Float16* asrc = Xe + (size_t)e * NSX * SLAB + (size_t)(mtbase + w) * 512 + lane * 8;
    // W staging: waves 0-3 stage G rows 8wv..8wv+7, waves 4-7 stage U rows.
    int wv = w & 3;
    const float* wsrc = ((w < 4) ? Wg : Wu) + (size_t)e * HD * IDIM + ig * 64;
    int rbase = 8 * wv;
    int rlo   = lane >> 4;          // 0..3
    int csl   = (lane & 15) * 4;    // f32 col slice within 64

    f32x4 accG[2][2], accU[2][2];
#pragma unroll
    for (int a_ = 0; a_ < 2; ++a_)
#pragma unroll
        for (int b_ = 0; b_ < 2; ++b_) {
            accG[a_][b_] = (f32x4){0.f, 0.f, 0.f, 0.f};
            accU[a_][b_] = (f32x4){0.f, 0.f, 0.f, 0.f};
        }

    f32x4 wr0[3], wr1[3];           // 3-step-deep W register pipeline

#define GU_WLOAD(KS, S)                                                        \
    { const float* p_ = wsrc + (size_t)((KS) * 32 + rbase) * IDIM;             \
      GLD128(wr0[S], p_ + (size_t)rlo * IDIM + csl);                           \
      GLD128(wr1[S], p_ + (size_t)(4 + rlo) * IDIM + csl); }

#define GU_WSTORE(KS, S)                                                       \
    { float (*LWp_)[66] = (w < 4) ? LG[(KS) & 3] : LU[(KS) & 3];               \
      DSW128(&LWp_[rbase + rlo][csl], wr0[S]);                                 \
      DSW128(&LWp_[rbase + 4 + rlo][csl], wr1[S]); }

#define GU_AGLOAD(KS) GLOAD16(asrc + (size_t)(KS) * SLAB, &LA[(KS) & 3][w * 512]);

#define GU_COMPUTE(KS)                                                         \
    { int B_ = (KS) & 3;                                                       \
      int c0 = wc * 32 + m16, c1 = c0 + 16;                                    \
      half8 bg0, bg1, bu0, bu1;                                                \
      _Pragma("unroll")                                                        \
      for (int j_ = 0; j_ < 8; ++j_) {                                         \
        bg0[j_] = (_Float16)LG[B_][q * 8 + j_][c0];                            \
        bg1[j_] = (_Float16)LG[B_][q * 8 + j_][c1];                            \
        bu0[j_] = (_Float16)LU[B_][q * 8 + j_][c0];                            \
        bu1[j_] = (_Float16)LU[B_][q * 8 + j_][c1];                            \
      }                                                                        \
      half8 a0 = *(const half8*)&LA[B_][wr * 512 + lane * 8];                  \
      half8 a1 = *(const half8*)&LA[B_][(wr + 4) * 512 + lane * 8];            \
      __builtin_amdgcn_s_setprio(1);                                           \
      accG[0][0] = __builtin_amdgcn_mfma_f32_16x16x32_f16(a0, bg0, accG[0][0], 0, 0, 0); \
      accG[0][1] = __builtin_amdgcn_mfma_f32_16x16x32_f16(a0, bg1, accG[0][1], 0, 0, 0); \
      accU[0][0] = __builtin_amdgcn_mfma_f32_16x16x32_f16(a0, bu0, accU[0][0], 0, 0, 0); \
      accU[0][1] = __builtin_amdgcn_mfma_f32_16x16x32_f16(a0, bu1, accU[0][1], 0, 0, 0); \
      accG[1][0] = __builtin_amdgcn_mfma_f32_16x16x32_f16(a1, bg0, accG[1][0], 0, 0, 0); \
      accG[1][1] = __builtin_amdgcn_mfma_f32_16x16x32_f16(a1, bg1, accG[1][1], 0, 0, 0); \
      accU[1][0] = __builtin_amdgcn_mfma_f32_16x16x32_f16(a1, bu0, accU[1][0], 0, 0, 0); \
      accU[1][1] = __builtin_amdgcn_mfma_f32_16x16x32_f16(a1, bu1, accU[1][1], 0, 0, 0); \
      __builtin_amdgcn_s_setprio(0); }

    constexpr int NK = HD / 32;   // 32
    // prologue: W 3 deep, A 2 deep; sched_barriers keep issue windows exact
    GU_WLOAD(0, 0)
    __builtin_amdgcn_sched_barrier(0);
    GU_WLOAD(1, 1) GU_AGLOAD(0)
    __builtin_amdgcn_sched_barrier(0);
    GU_WLOAD(2, 2) GU_AGLOAD(1)
    WAITVM(6);                      // Wregs[0] complete
    GU_WSTORE(0, 0)

#pragma unroll
    for (int ks = 0; ks < NK; ++ks) {
        __builtin_amdgcn_s_barrier();             // prior readers of reused bufs done
        if (ks + 3 < NK) GU_WLOAD(ks + 3, ks % 3)
        if (ks + 2 < NK) GU_AGLOAD(ks + 2)
        if      (ks + 4 <= NK) { WAITVM(6); }     // A[ks] + Wregs[ks+1] done
        else if (ks + 3 == NK) { WAITVM(4); }
        else if (ks + 2 == NK) { WAITVM(1); }
        else                   { WAITVM(0); }
        if (ks + 1 < NK) GU_WSTORE(ks + 1, (ks + 1) % 3)
        LGKM0;
        __builtin_amdgcn_s_barrier();             // buf ks published
        __builtin_amdgcn_sched_barrier(0);
        GU_COMPUTE(ks)
    }
#undef GU_WLOAD
#undef GU_WSTORE
#undef GU_AGLOAD
#undef GU_COMPUTE

    // store silu(g)*u into A in A-fragment slab order (for k_down's A-operand)
    int sa = ig * 2 + wc;                        // IDIM k-slab 0..15
    _Float16* aout = A + ((size_t)e * NSA + sa) * SLAB;
    int jp = m16 & 7;
#pragma unroll
    for (int mtl = 0; mtl < 2; ++mtl) {
        int mtg = mtbase + wr + 4 * mtl;
#pragma unroll
        for (int cg = 0; cg < 2; ++cg) {
            int qp = cg * 2 + (m16 >> 3);
#pragma unroll
            for (int r = 0; r < 4; ++r) {
                float g = accG[mtl][cg][r], u = accU[mtl][cg][r];
                float a = (g / (1.f + expf(-g))) * u;
                int lanep = qp * 16 + q * 4 + r;
                aout[((size_t)mtg * 64 + lanep) * 8 + jp] = (_Float16)a;
            }
        }
    }
}

// ---------------- Down ----------------
// 512 blocks (XCD-swizzled), 512 threads = 8 waves; tile 128 tok x 128 cols.
// Same hybrid staging: W (16 KB/step) via asm reg loads (2 per wave) 3 deep
// into padded LDS [32][130]; A via gload_lds. Same vmcnt ladder.
__global__ __launch_bounds__(512, 1) void k_down(
    const _Float16* __restrict__ A, const float* __restrict__ Wd,
    const int* __restrict__ cnt, const int* __restrict__ offs,
    const float* __restrict__ wl, float* __restrict__ Y)
{
    int bid  = blockIdx.x;
    int xcd  = bid & 7;
    int slot = bid >> 3;            // 0..63
    int e    = xcd * 4 + (slot & 3);
    int rest = slot >> 2;           // 0..15
    int hg   = rest & 7;            // 128-col group 0..7
    int tt   = rest >> 3;
    int n_e = cnt[e];
    if (tt * 128 >= n_e) return;
    int mtbase = tt * 8;
    int h0 = hg * 128;
    int tid  = threadIdx.x;
    int w    = tid >> 6;
    int lane = tid & 63;
    int m16 = lane & 15, q = lane >> 4;
    int wr = w & 3, wc = w >> 2;

    __shared__ __align__(16) float    LD[4][32][130];  // 66.6 KB (pad 128->130)
    __shared__ __align__(16) _Float16 LA[4][4096];     // 32 KB

    const _Float16* asrc = A + (size_t)e * NSA * SLAB + (size_t)(mtbase + w) * 512 + lane * 8;
    const float* dp = Wd + (size_t)e * IDIM * HD + h0;
    int rlo = lane >> 5;            // 0..1
    int csl = (lane & 31) * 4;      // f32 col slice within 128

    f32x4 acc[2][4];
#pragma unroll
    for (int a_ = 0; a_ < 2; ++a_)
#pragma unroll
        for (int b_ = 0; b_ < 4; ++b_) acc[a_][b_] = (f32x4){0.f, 0.f, 0.f, 0.f};

    f32x4 wr0[3], wr1[3];

#define DN_WLOAD(KS, S)                                                        \
    { const float* p_ = dp + (size_t)((KS) * 32 + 4 * w) * HD;                 \
      GLD128(wr0[S], p_ + (size_t)rlo * HD + csl);                             \
      GLD128(wr1[S], p_ + (size_t)(2 + rlo) * HD + csl); }

#define DN_WSTORE(KS, S)                                                       \
    { float (*LWp_)[130] = LD[(KS) & 3];                                       \
      DSW128(&LWp_[4 * w + rlo][csl], wr0[S]);                                 \
      DSW128(&LWp_[4 * w + 2 + rlo][csl], wr1[S]); }

#define DN_AGLOAD(KS) GLOAD16(asrc + (size_t)(KS) * SLAB, &LA[(KS) & 3][w * 512]);

#define DN_COMPUTE(KS)                                                         \
    { int B_ = (KS) & 3;                                                       \
      half8 bd[4];                                                             \
      _Pragma("unroll")                                                        \
      for (int cg = 0; cg < 4; ++cg) {                                         \
        int col = wc * 64 + cg * 16 + m16;                                     \
        _Pragma("unroll")                                                      \
        for (int j_ = 0; j_ < 8; ++j_) bd[cg][j_] = (_Float16)LD[B_][q * 8 + j_][col]; \
      }                                                                        \
      half8 a0 = *(const half8*)&LA[B_][wr * 512 + lane * 8];                  \
      half8 a1 = *(const half8*)&LA[B_][(wr + 4) * 512 + lane * 8];            \
      __builtin_amdgcn_s_setprio(1);                                           \
      _Pragma("unroll")                                                        \
      for (int cg = 0; cg < 4; ++cg) {                                         \
        acc[0][cg] = __builtin_amdgcn_mfma_f32_16x16x32_f16(a0, bd[cg], acc[0][cg], 0, 0, 0); \
        acc[1][cg] = __builtin_amdgcn_mfma_f32_16x16x32_f16(a1, bd[cg], acc[1][cg], 0, 0, 0); \
      }                                                                        \
      __builtin_amdgcn_s_setprio(0); }

    constexpr int NK = IDIM / 32;  // 16
    DN_WLOAD(0, 0)
    __builtin_amdgcn_sched_barrier(0);
    DN_WLOAD(1, 1) DN_AGLOAD(0)
    __builtin_amdgcn_sched_barrier(0);
    DN_WLOAD(2, 2) DN_AGLOAD(1)
    WAITVM(6);
    DN_WSTORE(0, 0)

#pragma unroll
    for (int ks = 0; ks < NK; ++ks) {
        __builtin_amdgcn_s_barrier();
        if (ks + 3 < NK) DN_WLOAD(ks + 3, ks % 3)
        if (ks + 2 < NK) DN_AGLOAD(ks + 2)
        if      (ks + 4 <= NK) { WAITVM(6); }
        else if (ks + 3 == NK) { WAITVM(4); }
        else if (ks + 2 == NK) { WAITVM(1); }
        else                   { WAITVM(0); }
        if (ks + 1 < NK) DN_WSTORE(ks + 1, (ks + 1) % 3)
        LGKM0;
        __builtin_amdgcn_s_barrier();
        __builtin_amdgcn_sched_barrier(0);
        DN_COMPUTE(ks)
    }
#undef DN_WLOAD
#undef DN_WSTORE
#undef DN_AGLOAD
#undef DN_COMPUTE

    int oe = offs[e];
#pragma unroll
    for (int mtl = 0; mtl < 2; ++mtl) {
        int mtg = wr + 4 * mtl;
#pragma unroll
        for (int cg = 0; cg < 4; ++cg) {
            int col = h0 + wc * 64 + cg * 16 + m16;
#pragma unroll
            for (int r = 0; r < 4; ++r) {
                int slot2 = tt * 128 + mtg * 16 + q * 4 + r;
                if (slot2 < n_e) {
                    float wt = wl[(size_t)e * TT + slot2];
                    Y[(size_t)(oe + slot2) * HD + col] = wt * acc[mtl][cg][r];
                }
            }
        }
    }
}

// ---------------- Combine: out[t] = sum of the token's 8 weighted partials ----
__global__ __launch_bounds__(256) void k_combine(
    const float* __restrict__ Y, const int* __restrict__ tslot,
    const int* __restrict__ offs, float* __restrict__ out)
{
    int t = blockIdx.x, tid = threadIdx.x;
    f32x4 s = (f32x4){0.f, 0.f, 0.f, 0.f};
#pragma unroll
    for (int r = 0; r < TOPK; ++r) {
        int ts  = tslot[t * TOPK + r];
        int e   = ts >> 8;            // TT = 256
        int pos = ts & 255;
        const float* yp = Y + (size_t)(offs[e] + pos) * HD + tid * 4;
        f32x4 v = *(const f32x4*)yp;
        s.x += v.x; s.y += v.y; s.z += v.z; s.w += v.w;
    }
    *(f32x4*)&out[(size_t)t * HD + tid * 4] = s;
}

extern "C" void kernel_launch(void* const* d_in, const int* in_sizes, int n_in,
                              void* d_out, int out_size, void* d_ws, size_t ws_size,
                              hipStream_t stream) {
    const float* x    = (const float*)d_in[0];
    const float* gw   = (const float*)d_in[1];
    const float* bias = (const float*)d_in[2];
    const float* Wg   = (const float*)d_in[3];
    const float* Wu   = (const float*)d_in[4];
    const float* Wd   = (const float*)d_in[5];
    float* out = (float*)d_out;   // reference output dtype is float32

    char* ws = (char*)d_ws;
    int*      cnt   = (int*)(ws + WS_CNT);
    int*      tok   = (int*)(ws + WS_TOK);
    float*    wl    = (float*)(ws + WS_WL);
    int*      tslot = (int*)(ws + WS_TSLOT);
    int*      offs  = (int*)(ws + WS_OFFS);
    _Float16* Xe    = (_Float16*)(ws + WS_XE);
    _Float16* A     = (_Float16*)(ws + WS_A);
    float*    Y     = (float*)(ws + WS_XE);   // aliases Xe (dead after k_gateup)

    hipMemsetAsync(ws, 0, 256, stream);       // expert counters

    k_route<<<TT, 256, 0, stream>>>(x, gw, bias, cnt, tok, wl, tslot);
    k_pack<<<NE * NSX, 256, 0, stream>>>(x, cnt, tok, Xe, offs);
    k_gateup<<<512, 512, 0, stream>>>(Xe, Wg, Wu, cnt, A);
    k_down<<<512, 512, 0, stream>>>(A, Wd, cnt, offs, wl, Y);
    k_combine<<<TT, 256, 0, stream>>>(Y, tslot, offs, out);
}